// Round 1
// baseline (2465.735 us; speedup 1.0000x reference)
//
#include <hip/hip_runtime.h>
#include <cstdint>
#include <cstddef>

#define NNODES 50000
#define NEDGES 800000
#define HID 128
#define NRBF 32
#define NGRAPH 500

// ---------------- embed: h[n,c] = emb[x[n],c] ----------------
__global__ void embed_kernel(const int* __restrict__ x, const float* __restrict__ emb,
                             float* __restrict__ h) {
  int i = blockIdx.x * blockDim.x + threadIdx.x;
  if (i >= NNODES * HID) return;
  int node = i >> 7, c = i & 127;
  h[i] = emb[x[node] * HID + c];
}

// ---------------- node GEMM: P[N,512] = h @ [Wf_d | Wf_s | Ws_d | Ws_s] (+bias on dst parts) ---
// block: 256 threads, tile 128 rows x 128 cols (one weight part), K=128 in chunks of 32.
// thread tile 8x8 (rows tr*8.., cols {tc*4..+3} and {64+tc*4..+3}).
__global__ __launch_bounds__(256) void node_gemm(
    const float* __restrict__ h, const float* __restrict__ Wf,
    const float* __restrict__ bf, const float* __restrict__ Ws,
    const float* __restrict__ bs, float* __restrict__ P, int N) {
  const int part = blockIdx.y;  // 0: Wf rows 0:128 (+bf), 1: Wf rows 128:256, 2: Ws rows 0:128 (+bs), 3: Ws rows 128:256
  const int row0 = blockIdx.x * 128;
  const float* W = ((part < 2) ? Wf : Ws) + ((part & 1) ? (128 * HID) : 0);
  const float* bias = (part == 0) ? bf : ((part == 2) ? bs : nullptr);

  __shared__ __align__(16) float hsT[32][132];  // [k][node], pad to 132 for alignment
  __shared__ __align__(16) float wsm[32][132];  // [k][col]

  const int tc = threadIdx.x & 15;
  const int tr = threadIdx.x >> 4;

  float acc[8][8];
#pragma unroll
  for (int i = 0; i < 8; ++i)
#pragma unroll
    for (int j = 0; j < 8; ++j) acc[i][j] = 0.f;

  for (int kc = 0; kc < HID; kc += 32) {
    // stage h tile transposed: 128 nodes x 32 k
#pragma unroll
    for (int j = 0; j < 4; ++j) {
      int i = threadIdx.x + 256 * j;
      int node = i >> 3;
      int kq = i & 7;
      int grow = row0 + node;
      if (grow >= N) grow = N - 1;  // pad rows: garbage ok, stores guarded
      const float4 v = *(const float4*)&h[(size_t)grow * HID + kc + kq * 4];
      hsT[kq * 4 + 0][node] = v.x;
      hsT[kq * 4 + 1][node] = v.y;
      hsT[kq * 4 + 2][node] = v.z;
      hsT[kq * 4 + 3][node] = v.w;
    }
    // stage weight chunk: 32 k x 128 cols
#pragma unroll
    for (int j = 0; j < 4; ++j) {
      int i = threadIdx.x + 256 * j;
      int kk = i >> 5;
      int colq = i & 31;
      *(float4*)&wsm[kk][colq * 4] = *(const float4*)&W[(size_t)(kc + kk) * HID + colq * 4];
    }
    __syncthreads();
#pragma unroll
    for (int k = 0; k < 32; ++k) {
      float4 a0 = *(const float4*)&hsT[k][tr * 8];
      float4 a1 = *(const float4*)&hsT[k][tr * 8 + 4];
      float4 b0 = *(const float4*)&wsm[k][tc * 4];
      float4 b1 = *(const float4*)&wsm[k][tc * 4 + 64];
      float av[8] = {a0.x, a0.y, a0.z, a0.w, a1.x, a1.y, a1.z, a1.w};
      float bv[8] = {b0.x, b0.y, b0.z, b0.w, b1.x, b1.y, b1.z, b1.w};
#pragma unroll
      for (int i = 0; i < 8; ++i)
#pragma unroll
        for (int jj = 0; jj < 8; ++jj) acc[i][jj] += av[i] * bv[jj];
    }
    __syncthreads();
  }

  const int colBase = part * HID;
  float badd[8];
#pragma unroll
  for (int half = 0; half < 2; ++half)
#pragma unroll
    for (int u = 0; u < 4; ++u)
      badd[half * 4 + u] = bias ? bias[half * 64 + tc * 4 + u] : 0.f;

#pragma unroll
  for (int i = 0; i < 8; ++i) {
    int row = row0 + tr * 8 + i;
    if (row >= N) continue;
#pragma unroll
    for (int half = 0; half < 2; ++half) {
      float4 o;
      o.x = acc[i][half * 4 + 0] + badd[half * 4 + 0];
      o.y = acc[i][half * 4 + 1] + badd[half * 4 + 1];
      o.z = acc[i][half * 4 + 2] + badd[half * 4 + 2];
      o.w = acc[i][half * 4 + 3] + badd[half * 4 + 3];
      *(float4*)&P[(size_t)row * 512 + colBase + half * 64 + tc * 4] = o;
    }
  }
}

// ---------------- edge kernel: msg = sigmoid(zf)*softplus(zs), atomic scatter to agg[dst] ---
// 256 threads = 2 edges per block-iteration; 128 threads per edge (one output col each).
// Edge-weight slice (rows 256:288 of Wf/Ws) held in registers (column c fixed per thread).
__global__ __launch_bounds__(256) void edge_kernel(
    const float* __restrict__ P, const float* __restrict__ eattr,
    const float* __restrict__ Wf, const float* __restrict__ Ws,
    const int* __restrict__ src, const int* __restrict__ dst,
    float* __restrict__ agg, int E) {
  const int c = threadIdx.x & 127;
  const int half = threadIdx.x >> 7;

  float wf[NRBF], ws[NRBF];
#pragma unroll
  for (int k = 0; k < NRBF; ++k) {
    wf[k] = Wf[(size_t)(256 + k) * HID + c];
    ws[k] = Ws[(size_t)(256 + k) * HID + c];
  }

  const int npairs = E >> 1;
  for (int p = blockIdx.x; p < npairs; p += gridDim.x) {
    int e = p * 2 + half;
    e = __builtin_amdgcn_readfirstlane(e);  // wave-uniform -> scalar loads
    const int s = src[e];
    const int d = dst[e];
    const float* ep = eattr + (size_t)e * NRBF;
    float af = 0.f, as = 0.f;
#pragma unroll
    for (int k = 0; k < NRBF; ++k) {
      float ev = ep[k];
      af += ev * wf[k];
      as += ev * ws[k];
    }
    const float* pd = P + (size_t)d * 512;
    const float* ps = P + (size_t)s * 512;
    float zf = pd[c] + ps[HID + c] + af;          // bias bf already folded into part 0
    float zs = pd[256 + c] + ps[384 + c] + as;    // bias bs folded into part 2
    float sig = 1.f / (1.f + __expf(-zf));
    float sp = (zs > 20.f) ? zs : log1pf(__expf(zs));
    atomicAdd(&agg[(size_t)d * HID + c], sig * sp);
  }
}

// ---------------- h = relu(h + agg) ----------------
__global__ void relu_add(float* __restrict__ h, const float* __restrict__ agg) {
  int i = blockIdx.x * blockDim.x + threadIdx.x;
  if (i >= NNODES * HID) return;
  float v = h[i] + agg[i];
  h[i] = v > 0.f ? v : 0.f;
}

// ---------------- pooling: segment sums + counts ----------------
__global__ void pool_kernel(const float* __restrict__ h, const int* __restrict__ batch,
                            float* __restrict__ sums, float* __restrict__ counts) {
  int i = blockIdx.x * blockDim.x + threadIdx.x;
  if (i >= NNODES * HID) return;
  int node = i >> 7, c = i & 127;
  int g = batch[node];
  atomicAdd(&sums[(size_t)g * HID + c], h[i]);
  if (c == 0) atomicAdd(&counts[g], 1.f);
}

// ---------------- out[g] = (sums[g]/max(cnt,1)) @ Wlin + blin ----------------
__global__ __launch_bounds__(128) void final_kernel(
    const float* __restrict__ sums, const float* __restrict__ counts,
    const float* __restrict__ Wlin, const float* __restrict__ blin,
    float* __restrict__ out) {
  int g = blockIdx.x;
  int c = threadIdx.x;
  __shared__ float pool[HID];
  float cnt = counts[g];
  cnt = cnt > 1.f ? cnt : 1.f;
  pool[c] = sums[(size_t)g * HID + c] / cnt;
  __syncthreads();
  float acc = blin[c];
#pragma unroll 8
  for (int k = 0; k < HID; ++k) acc += pool[k] * Wlin[k * HID + c];
  out[(size_t)g * HID + c] = acc;
}

extern "C" void kernel_launch(void* const* d_in, const int* in_sizes, int n_in,
                              void* d_out, int out_size, void* d_ws, size_t ws_size,
                              hipStream_t stream) {
  const int* x = (const int*)d_in[0];
  const int* eidx = (const int*)d_in[1];
  const float* eattr = (const float*)d_in[2];
  const int* batch = (const int*)d_in[3];
  const float* emb = (const float*)d_in[4];
  const float* Wf[3] = {(const float*)d_in[5], (const float*)d_in[9], (const float*)d_in[13]};
  const float* bf[3] = {(const float*)d_in[6], (const float*)d_in[10], (const float*)d_in[14]};
  const float* Ws[3] = {(const float*)d_in[7], (const float*)d_in[11], (const float*)d_in[15]};
  const float* bs[3] = {(const float*)d_in[8], (const float*)d_in[12], (const float*)d_in[16]};
  const float* Wlin = (const float*)d_in[17];
  const float* blin = (const float*)d_in[18];
  const int* srcp = eidx;            // edge_index[0]
  const int* dstp = eidx + NEDGES;   // edge_index[1]

  float* wsf = (float*)d_ws;
  float* h = wsf;                                  // N*128
  float* P = h + (size_t)NNODES * HID;             // N*512
  float* agg = P + (size_t)NNODES * 512;           // N*128
  float* sums = agg + (size_t)NNODES * HID;        // 500*128
  float* counts = sums + (size_t)NGRAPH * HID;     // 500

  const int nelem = NNODES * HID;
  embed_kernel<<<(nelem + 255) / 256, 256, 0, stream>>>(x, emb, h);

  dim3 ggrid((NNODES + 127) / 128, 4);
  for (int l = 0; l < 3; ++l) {
    hipMemsetAsync(agg, 0, (size_t)nelem * sizeof(float), stream);
    node_gemm<<<ggrid, 256, 0, stream>>>(h, Wf[l], bf[l], Ws[l], bs[l], P, NNODES);
    edge_kernel<<<2048, 256, 0, stream>>>(P, eattr, Wf[l], Ws[l], srcp, dstp, agg, NEDGES);
    relu_add<<<(nelem + 255) / 256, 256, 0, stream>>>(h, agg);
  }

  hipMemsetAsync(sums, 0, (size_t)(NGRAPH * HID + NGRAPH) * sizeof(float), stream);
  pool_kernel<<<(nelem + 255) / 256, 256, 0, stream>>>(h, batch, sums, counts);
  final_kernel<<<NGRAPH, 128, 0, stream>>>(sums, counts, Wlin, blin, (float*)d_out);
}